// Round 1
// baseline (292.278 us; speedup 1.0000x reference)
//
#include <hip/hip_runtime.h>

#define KDIM 768
#define MANS 640      // L*B*T = 2*16*20
#define VV   30000
#define VPAD 30080    // 235 * 128

typedef __attribute__((ext_vector_type(4))) float  f32x4;
typedef __attribute__((ext_vector_type(8))) __bf16 bf16x8;

__device__ __forceinline__ unsigned short f2bf(float f) {
    union { float f; unsigned int u; } v; v.f = f;
    unsigned int r = v.u + 0x7fffu + ((v.u >> 16) & 1u);  // RNE
    return (unsigned short)(r >> 16);
}

__global__ __launch_bounds__(256) void cvt_bf16(const float* __restrict__ s,
                                                unsigned short* __restrict__ d, int n4) {
    int i = blockIdx.x * blockDim.x + threadIdx.x;
    if (i >= n4) return;
    f32x4 v = ((const f32x4*)s)[i];
    ushort4 o;
    o.x = f2bf(v.x); o.y = f2bf(v.y); o.z = f2bf(v.z); o.w = f2bf(v.w);
    ((ushort4*)d)[i] = o;
}

// out[m][n] = sum_k A[m][k] * B[n][k]  (NT gemm, both row-major [rows][768])
// Block tile 128x128, BK=32, 4 waves in 2x2, each wave 64x64 via 4x4 MFMA 16x16x32.
template<bool A_F32, bool BIAS_BF16_OUT>
__global__ __launch_bounds__(256) void gemm_bt(
    const void* __restrict__ Av, const unsigned short* __restrict__ Bp,
    const float* __restrict__ bias, void* __restrict__ outv,
    int aRowMax, int nValid, int outStride)
{
    __shared__ unsigned short sA[128 * 32];
    __shared__ unsigned short sB[128 * 32];

    const int t    = threadIdx.x;
    const int lane = t & 63;
    const int w    = t >> 6;
    const int quad = lane >> 4;
    const int lr   = lane & 15;
    const int wm   = w >> 1;
    const int wn   = w & 1;
    const long m0  = (long)blockIdx.x * 128;
    const long n0  = (long)blockIdx.y * 128;

    f32x4 acc[4][4];
#pragma unroll
    for (int i = 0; i < 4; ++i)
#pragma unroll
        for (int j = 0; j < 4; ++j)
            acc[i][j] = (f32x4){0.f, 0.f, 0.f, 0.f};

    const float*          Af = (const float*)Av;
    const unsigned short* Ab = (const unsigned short*)Av;

    for (int k0 = 0; k0 < KDIM; k0 += 32) {
        // ---- stage A tile [128][32] as bf16, 16B chunks XOR-swizzled ----
#pragma unroll
        for (int j = 0; j < 2; ++j) {
            int f   = j * 256 + t;
            int row = f >> 2;
            int kc  = f & 3;
            int p   = kc ^ ((row >> 2) & 3);
            long grow = m0 + row;
            if (grow > aRowMax) grow = aRowMax;   // clamp (pad rows read dup data)
            unsigned short* dst = &sA[row * 32 + p * 8];
            if (A_F32) {
                const float* g = Af + grow * KDIM + k0 + kc * 8;
                f32x4 v0 = *(const f32x4*)g;
                f32x4 v1 = *(const f32x4*)(g + 4);
                ushort4 a, b;
                a.x = f2bf(v0.x); a.y = f2bf(v0.y); a.z = f2bf(v0.z); a.w = f2bf(v0.w);
                b.x = f2bf(v1.x); b.y = f2bf(v1.y); b.z = f2bf(v1.z); b.w = f2bf(v1.w);
                ((ushort4*)dst)[0] = a;
                ((ushort4*)dst)[1] = b;
            } else {
                *(uint4*)dst = *(const uint4*)(Ab + grow * KDIM + k0 + kc * 8);
            }
        }
        // ---- stage B tile [128][32] bf16 ----
#pragma unroll
        for (int j = 0; j < 2; ++j) {
            int f   = j * 256 + t;
            int row = f >> 2;
            int kc  = f & 3;
            int p   = kc ^ ((row >> 2) & 3);
            *(uint4*)&sB[row * 32 + p * 8] =
                *(const uint4*)(Bp + (n0 + row) * KDIM + k0 + kc * 8);
        }
        __syncthreads();

        // ---- fragments: lane holds [m|n = lr][k = quad*8 + j] ----
        bf16x8 af[4], bfrag[4];
#pragma unroll
        for (int i = 0; i < 4; ++i) {
            int row = wm * 64 + i * 16 + lr;
            int p   = quad ^ ((row >> 2) & 3);
            af[i]   = *(const bf16x8*)&sA[row * 32 + p * 8];
        }
#pragma unroll
        for (int jn = 0; jn < 4; ++jn) {
            int row   = wn * 64 + jn * 16 + lr;
            int p     = quad ^ ((row >> 2) & 3);
            bfrag[jn] = *(const bf16x8*)&sB[row * 32 + p * 8];
        }
#pragma unroll
        for (int i = 0; i < 4; ++i)
#pragma unroll
            for (int jn = 0; jn < 4; ++jn)
                acc[i][jn] = __builtin_amdgcn_mfma_f32_16x16x32_bf16(
                    af[i], bfrag[jn], acc[i][jn], 0, 0, 0);
        __syncthreads();
    }

    // ---- epilogue: C/D frag -> row = quad*4 + r, col = lr ----
    if (BIAS_BF16_OUT) {
        unsigned short* outp = (unsigned short*)outv;
#pragma unroll
        for (int i = 0; i < 4; ++i)
#pragma unroll
            for (int jn = 0; jn < 4; ++jn) {
                long n   = n0 + wn * 64 + jn * 16 + lr;
                float bv = bias[n];
#pragma unroll
                for (int r = 0; r < 4; ++r) {
                    long m = m0 + wm * 64 + i * 16 + quad * 4 + r;
                    outp[m * (long)outStride + n] = f2bf(acc[i][jn][r] + bv);
                }
            }
    } else {
        float* outp = (float*)outv;
#pragma unroll
        for (int i = 0; i < 4; ++i)
#pragma unroll
            for (int jn = 0; jn < 4; ++jn) {
                long n = n0 + wn * 64 + jn * 16 + lr;
                if (n < nValid) {
#pragma unroll
                    for (int r = 0; r < 4; ++r) {
                        long m = m0 + wm * 64 + i * 16 + quad * 4 + r;
                        outp[m * (long)outStride + n] = acc[i][jn][r];
                    }
                }
            }
    }
}

extern "C" void kernel_launch(void* const* d_in, const int* in_sizes, int n_in,
                              void* d_out, int out_size, void* d_ws, size_t ws_size,
                              hipStream_t stream) {
    const float* answer = (const float*)d_in[0];   // [640][768] f32
    const float* vocab  = (const float*)d_in[1];   // [30000][768] f32
    const float* W      = (const float*)d_in[2];   // [768][768] f32
    const float* bvec   = (const float*)d_in[3];   // [768] f32

    char* ws = (char*)d_ws;
    unsigned short* VC  = (unsigned short*)ws;                                   // [30080][768] bf16
    unsigned short* Abf = (unsigned short*)(ws + (size_t)VPAD * KDIM * 2);       // [640][768]  bf16
    unsigned short* Wbf = (unsigned short*)(ws + (size_t)VPAD * KDIM * 2
                                               + (size_t)MANS * KDIM * 2);       // [768][768]  bf16

    {   // answer -> bf16
        int n4 = MANS * KDIM / 4;
        cvt_bf16<<<(n4 + 255) / 256, 256, 0, stream>>>(answer, Abf, n4);
    }
    {   // W -> bf16
        int n4 = KDIM * KDIM / 4;
        cvt_bf16<<<(n4 + 255) / 256, 256, 0, stream>>>(W, Wbf, n4);
    }
    {   // VC[v][d] = sum_k vocab[v][k] * W[d][k] + b[d]   (bf16 out, padded rows)
        dim3 grid(VPAD / 128, KDIM / 128);
        gemm_bt<true, true><<<grid, 256, 0, stream>>>(
            (const void*)vocab, Wbf, bvec, (void*)VC, VV - 1, KDIM, KDIM);
    }
    {   // out[m][v] = sum_k Abf[m][k] * VC[v][k]   (f32 out, v < 30000 guard)
        dim3 grid(MANS / 128, VPAD / 128);
        gemm_bt<false, false><<<grid, 256, 0, stream>>>(
            (const void*)Abf, VC, nullptr, d_out, MANS - 1, VV, VV);
    }
}

// Round 2
// 251.277 us; speedup vs baseline: 1.1632x; 1.1632x over previous
//
#include <hip/hip_runtime.h>

#define KDIM 768
#define MANS 640      // L*B*T = 2*16*20
#define VV   30000
#define VPAD 30080    // 235 * 128

typedef __attribute__((ext_vector_type(4))) float  f32x4;
typedef __attribute__((ext_vector_type(8))) __bf16 bf16x8;

__device__ __forceinline__ unsigned short f2bf(float f) {
    union { float f; unsigned int u; } v; v.f = f;
    unsigned int r = v.u + 0x7fffu + ((v.u >> 16) & 1u);  // RNE
    return (unsigned short)(r >> 16);
}

__device__ __forceinline__ void load_lds16(const unsigned short* g, unsigned short* l) {
    __builtin_amdgcn_global_load_lds(
        (__attribute__((address_space(1))) void*)(void*)g,
        (__attribute__((address_space(3))) void*)l,
        16, 0, 0);
}

// ---- fp32 -> bf16, 8 elements/thread, grid covers exactly n8 threads ----
__global__ __launch_bounds__(256) void cvt8(const float* __restrict__ s,
                                            unsigned short* __restrict__ d) {
    long i = (long)blockIdx.x * 256 + threadIdx.x;
    const f32x4* p = (const f32x4*)s + i * 2;
    f32x4 v0 = p[0], v1 = p[1];
    ushort4 o0, o1;
    o0.x = f2bf(v0.x); o0.y = f2bf(v0.y); o0.z = f2bf(v0.z); o0.w = f2bf(v0.w);
    o1.x = f2bf(v1.x); o1.y = f2bf(v1.y); o1.z = f2bf(v1.z); o1.w = f2bf(v1.w);
    ((ushort4*)d)[i * 2]     = o0;
    ((ushort4*)d)[i * 2 + 1] = o1;
}

// ---- W[768][768] f32 -> Wt[k][d] = W[d][k] bf16 ----
__global__ __launch_bounds__(256) void transpose_cvt(const float* __restrict__ W,
                                                     unsigned short* __restrict__ Wt) {
    __shared__ float s[64][65];
    const int bx = blockIdx.x * 64;   // col base of W
    const int by = blockIdx.y * 64;   // row base of W
    const int tx = threadIdx.x & 63;
    const int tg = threadIdx.x >> 6;
#pragma unroll
    for (int i = 0; i < 16; ++i) {
        int r = tg * 16 + i;
        s[r][tx] = W[(long)(by + r) * KDIM + bx + tx];
    }
    __syncthreads();
#pragma unroll
    for (int i = 0; i < 16; ++i) {
        int r = tg * 16 + i;
        Wt[(long)(bx + r) * KDIM + by + tx] = f2bf(s[tx][r]);
    }
}

// ---- c[m] = dot(A[m], b), fp32, one wave per row ----
__global__ __launch_bounds__(256) void dot_b(const float* __restrict__ A,
                                             const float* __restrict__ b,
                                             float* __restrict__ c) {
    int row  = blockIdx.x * 4 + (threadIdx.x >> 6);
    int lane = threadIdx.x & 63;
    const float* ap = A + (long)row * KDIM;
    float s = 0.f;
#pragma unroll
    for (int i = 0; i < KDIM / 64; ++i) s += ap[i * 64 + lane] * b[i * 64 + lane];
#pragma unroll
    for (int off = 32; off; off >>= 1) s += __shfl_down(s, off, 64);
    if (lane == 0) c[row] = s;
}

// =====================================================================
// Small GEMM (round-1 structure): out[m][n] = sum_k A[m][k]*B[n][k]
// A fp32 (cvt in-register), B bf16. bf16 out. Used for A2 = A @ W.
// =====================================================================
__global__ __launch_bounds__(256) void gemm_a2(
    const float* __restrict__ Af, const unsigned short* __restrict__ Bp,
    unsigned short* __restrict__ outp)
{
    __shared__ unsigned short sA[128 * 32];
    __shared__ unsigned short sB[128 * 32];

    const int t    = threadIdx.x;
    const int lane = t & 63;
    const int w    = t >> 6;
    const int quad = lane >> 4;
    const int lr   = lane & 15;
    const int wm   = w >> 1;
    const int wn   = w & 1;
    const long m0  = (long)blockIdx.x * 128;
    const long n0  = (long)blockIdx.y * 128;

    f32x4 acc[4][4];
#pragma unroll
    for (int i = 0; i < 4; ++i)
#pragma unroll
        for (int j = 0; j < 4; ++j)
            acc[i][j] = (f32x4){0.f, 0.f, 0.f, 0.f};

    for (int k0 = 0; k0 < KDIM; k0 += 32) {
#pragma unroll
        for (int j = 0; j < 2; ++j) {
            int f   = j * 256 + t;
            int row = f >> 2;
            int kc  = f & 3;
            int p   = kc ^ ((row >> 2) & 3);
            unsigned short* dst = &sA[row * 32 + p * 8];
            const float* g = Af + (m0 + row) * KDIM + k0 + kc * 8;
            f32x4 v0 = *(const f32x4*)g;
            f32x4 v1 = *(const f32x4*)(g + 4);
            ushort4 a, b;
            a.x = f2bf(v0.x); a.y = f2bf(v0.y); a.z = f2bf(v0.z); a.w = f2bf(v0.w);
            b.x = f2bf(v1.x); b.y = f2bf(v1.y); b.z = f2bf(v1.z); b.w = f2bf(v1.w);
            ((ushort4*)dst)[0] = a;
            ((ushort4*)dst)[1] = b;
        }
#pragma unroll
        for (int j = 0; j < 2; ++j) {
            int f   = j * 256 + t;
            int row = f >> 2;
            int kc  = f & 3;
            int p   = kc ^ ((row >> 2) & 3);
            *(uint4*)&sB[row * 32 + p * 8] =
                *(const uint4*)(Bp + (n0 + row) * KDIM + k0 + kc * 8);
        }
        __syncthreads();

        bf16x8 af[4], bfrag[4];
#pragma unroll
        for (int i = 0; i < 4; ++i) {
            int row = wm * 64 + i * 16 + lr;
            int p   = quad ^ ((row >> 2) & 3);
            af[i]   = *(const bf16x8*)&sA[row * 32 + p * 8];
        }
#pragma unroll
        for (int jn = 0; jn < 4; ++jn) {
            int row   = wn * 64 + jn * 16 + lr;
            int p     = quad ^ ((row >> 2) & 3);
            bfrag[jn] = *(const bf16x8*)&sB[row * 32 + p * 8];
        }
#pragma unroll
        for (int i = 0; i < 4; ++i)
#pragma unroll
            for (int jn = 0; jn < 4; ++jn)
                acc[i][jn] = __builtin_amdgcn_mfma_f32_16x16x32_bf16(
                    af[i], bfrag[jn], acc[i][jn], 0, 0, 0);
        __syncthreads();
    }

#pragma unroll
    for (int i = 0; i < 4; ++i)
#pragma unroll
        for (int jn = 0; jn < 4; ++jn) {
            long n = n0 + wn * 64 + jn * 16 + lr;
#pragma unroll
            for (int r = 0; r < 4; ++r) {
                long m = m0 + wm * 64 + i * 16 + quad * 4 + r;
                outp[m * KDIM + n] = f2bf(acc[i][jn][r]);
            }
        }
}

// =====================================================================
// Big GEMM (m97-style global_load_lds staging, source-permuted XOR swizzle)
// out[m][v] = sum_k A[m][k]*B[v][k] + c[m], fp32 out, v<nValid guard.
// =====================================================================
__global__ __launch_bounds__(256) void gemm_lds(
    const unsigned short* __restrict__ A, const unsigned short* __restrict__ B,
    const float* __restrict__ cvec, float* __restrict__ outp,
    int nValid, int outStride)
{
    __shared__ unsigned short sA[128 * 32];
    __shared__ unsigned short sB[128 * 32];

    const int t    = threadIdx.x;
    const int lane = t & 63;
    const int w    = t >> 6;
    const int quad = lane >> 4;
    const int lr   = lane & 15;
    const int wm   = w >> 1;
    const int wn   = w & 1;
    const long m0  = (long)blockIdx.x * 128;
    const long n0  = (long)blockIdx.y * 128;

    f32x4 acc[4][4];
#pragma unroll
    for (int i = 0; i < 4; ++i)
#pragma unroll
        for (int j = 0; j < 4; ++j)
            acc[i][j] = (f32x4){0.f, 0.f, 0.f, 0.f};

    // Staging: 512 16B-chunks per tile. Wave w, inst j covers slots
    // [(j*4+w)*64, +64). Slot s holds chunk (row=s>>2, kc=(s&3)^((row>>2)&3)).
    // LDS dst is wave-uniform base + lane*16 (global_load_lds semantics);
    // the XOR swizzle is applied on the global source side.
    const int s0 = w * 64 + lane;
    const int r0 = s0 >> 2, c0 = (s0 & 3) ^ ((r0 >> 2) & 3);
    const int s1 = (4 + w) * 64 + lane;
    const int r1 = s1 >> 2, c1 = (s1 & 3) ^ ((r1 >> 2) & 3);

    const unsigned short* ga0 = A + (m0 + r0) * KDIM + c0 * 8;
    const unsigned short* ga1 = A + (m0 + r1) * KDIM + c1 * 8;
    const unsigned short* gb0 = B + (n0 + r0) * KDIM + c0 * 8;
    const unsigned short* gb1 = B + (n0 + r1) * KDIM + c1 * 8;
    unsigned short* la0 = &sA[(0 + w) * 512];
    unsigned short* la1 = &sA[(4 + w) * 512];
    unsigned short* lb0 = &sB[(0 + w) * 512];
    unsigned short* lb1 = &sB[(4 + w) * 512];

    for (int k0 = 0; k0 < KDIM; k0 += 32) {
        load_lds16(ga0 + k0, la0);
        load_lds16(ga1 + k0, la1);
        load_lds16(gb0 + k0, lb0);
        load_lds16(gb1 + k0, lb1);
        __syncthreads();

        bf16x8 af[4], bfrag[4];
#pragma unroll
        for (int i = 0; i < 4; ++i) {
            int row = wm * 64 + i * 16 + lr;
            int p   = quad ^ ((row >> 2) & 3);
            af[i]   = *(const bf16x8*)&sA[row * 32 + p * 8];
        }
#pragma unroll
        for (int jn = 0; jn < 4; ++jn) {
            int row   = wn * 64 + jn * 16 + lr;
            int p     = quad ^ ((row >> 2) & 3);
            bfrag[jn] = *(const bf16x8*)&sB[row * 32 + p * 8];
        }
#pragma unroll
        for (int i = 0; i < 4; ++i)
#pragma unroll
            for (int jn = 0; jn < 4; ++jn)
                acc[i][jn] = __builtin_amdgcn_mfma_f32_16x16x32_bf16(
                    af[i], bfrag[jn], acc[i][jn], 0, 0, 0);
        __syncthreads();
    }

#pragma unroll
    for (int i = 0; i < 4; ++i) {
#pragma unroll
        for (int jn = 0; jn < 4; ++jn) {
            long n = n0 + wn * 64 + jn * 16 + lr;
            if (n < nValid) {
#pragma unroll
                for (int r = 0; r < 4; ++r) {
                    long m  = m0 + wm * 64 + i * 16 + quad * 4 + r;
                    float cv = cvec[m];
                    outp[m * (long)outStride + n] = acc[i][jn][r] + cv;
                }
            }
        }
    }
}

extern "C" void kernel_launch(void* const* d_in, const int* in_sizes, int n_in,
                              void* d_out, int out_size, void* d_ws, size_t ws_size,
                              hipStream_t stream) {
    const float* answer = (const float*)d_in[0];   // [640][768] f32
    const float* vocab  = (const float*)d_in[1];   // [30000][768] f32
    const float* W      = (const float*)d_in[2];   // [768][768] f32
    const float* bvec   = (const float*)d_in[3];   // [768] f32

    // ws layout (bytes): vocab_bf first so its 80 pad rows alias the trailing
    // buffers (reads only; polluted accumulator columns are v>=30000, never
    // stored). Total 48,245,248 B <= round-1-proven 48.36 MB.
    char* ws = (char*)d_ws;
    unsigned short* vocab_bf = (unsigned short*)ws;                               // [30000][768] bf16
    unsigned short* Wt_bf    = (unsigned short*)(ws + 46080000);                  // [768][768]  bf16 (transposed)
    unsigned short* A2_bf    = (unsigned short*)(ws + 46080000 + 1179648);        // [640][768]  bf16
    float*          cptr     = (float*)         (ws + 46080000 + 1179648 + 983040); // [640] f32

    // 1. vocab -> bf16 (exactly 30000*768/8 = 2,880,000 threads)
    cvt8<<<11250, 256, 0, stream>>>(vocab, vocab_bf);

    // 2. W -> Wt bf16 (transpose)
    transpose_cvt<<<dim3(12, 12), 256, 0, stream>>>(W, Wt_bf);

    // 3. c[m] = dot(A[m], b)
    dot_b<<<160, 256, 0, stream>>>(answer, bvec, cptr);

    // 4. A2[m][k] = sum_d A[m][d] * W[d][k]  (= sum_d A[m][d] * Wt[k][d])
    gemm_a2<<<dim3(5, 6), 256, 0, stream>>>(answer, Wt_bf, A2_bf);

    // 5. out[m][v] = sum_k A2[m][k] * vocab_bf[v][k] + c[m]
    gemm_lds<<<dim3(5, 235), 256, 0, stream>>>(A2_bf, vocab_bf, cptr,
                                               (float*)d_out, VV, VV);
}

// Round 3
// 232.002 us; speedup vs baseline: 1.2598x; 1.0831x over previous
//
#include <hip/hip_runtime.h>

#define KDIM 768
#define MANS 640      // L*B*T
#define VV   30000
#define VPAD 30080

typedef __attribute__((ext_vector_type(4)))  float  f32x4;
typedef __attribute__((ext_vector_type(16))) float  f32x16;
typedef __attribute__((ext_vector_type(8)))  __bf16 bf16x8;

__device__ __forceinline__ unsigned short f2bf(float f) {
    union { float f; unsigned int u; } v; v.f = f;
    unsigned int r = v.u + 0x7fffu + ((v.u >> 16) & 1u);  // RNE
    return (unsigned short)(r >> 16);
}

__device__ __forceinline__ void load_lds16(const unsigned short* g, unsigned short* l) {
    __builtin_amdgcn_global_load_lds(
        (__attribute__((address_space(1))) void*)(void*)g,
        (__attribute__((address_space(3))) void*)l,
        16, 0, 0);
}

// ===================== fused prep =====================
// blocks [0,11250):    vocab f32 -> bf16 (8 elem/thread)
// blocks [11250,11394): W[768][768] -> Wt[k][d]=W[d][k] bf16 (64x64 tiles)
// blocks [11394,11554): c[m] = dot(answer[m], b)
#define PREP_CVT 11250
#define PREP_TRN 11394
#define PREP_TOT 11554

__global__ __launch_bounds__(256) void prep(
    const float* __restrict__ vocab, const float* __restrict__ W,
    const float* __restrict__ A, const float* __restrict__ b,
    unsigned short* __restrict__ vocab_bf, unsigned short* __restrict__ Wt_bf,
    float* __restrict__ cvec)
{
    __shared__ float ts[64][65];
    const int blk = blockIdx.x;
    if (blk < PREP_CVT) {
        long i = (long)blk * 256 + threadIdx.x;
        const f32x4* p = (const f32x4*)vocab + i * 2;
        f32x4 v0 = p[0], v1 = p[1];
        ushort4 o0, o1;
        o0.x = f2bf(v0.x); o0.y = f2bf(v0.y); o0.z = f2bf(v0.z); o0.w = f2bf(v0.w);
        o1.x = f2bf(v1.x); o1.y = f2bf(v1.y); o1.z = f2bf(v1.z); o1.w = f2bf(v1.w);
        ((ushort4*)vocab_bf)[i * 2]     = o0;
        ((ushort4*)vocab_bf)[i * 2 + 1] = o1;
    } else if (blk < PREP_TRN) {
        int tb = blk - PREP_CVT;
        int bx = (tb % 12) * 64, by = (tb / 12) * 64;
        int tx = threadIdx.x & 63, tg = threadIdx.x >> 6;
#pragma unroll
        for (int i = 0; i < 16; ++i) {
            int r = tg * 16 + i;
            ts[r][tx] = W[(long)(by + r) * KDIM + bx + tx];
        }
        __syncthreads();
#pragma unroll
        for (int i = 0; i < 16; ++i) {
            int r = tg * 16 + i;
            Wt_bf[(long)(bx + r) * KDIM + by + tx] = f2bf(ts[tx][r]);
        }
    } else {
        int row  = (blk - PREP_TRN) * 4 + (threadIdx.x >> 6);
        int lane = threadIdx.x & 63;
        const float* ap = A + (long)row * KDIM;
        float s = 0.f;
#pragma unroll
        for (int i = 0; i < KDIM / 64; ++i) s += ap[i * 64 + lane] * b[i * 64 + lane];
#pragma unroll
        for (int off = 32; off; off >>= 1) s += __shfl_down(s, off, 64);
        if (lane == 0) cvec[row] = s;
    }
}

// ===================== 32x32x16 MFMA NT-GEMM template =====================
// out[m][n] = sum_k A[m][k]*B[n][k]. Block tile TM x TN, BK=64, 4 waves (2x2),
// wave tile (TM/2)x(TN/2) as FMxFN frags of 32x32. LDS slot swizzle:
// slot s <-> (row=s>>3, chunk c=(s&7)^(row&7)), 16B chunks. global_load_lds
// dest = wave-uniform base + lane*16; swizzle applied on the SOURCE side.
// A frag: [m=lane&31][k=(lane>>5)*8+j]; C/D: col=lane&31,
// row=(reg&3)+8*(reg>>2)+4*(lane>>5)  (m74/m101-verified).
template<int TM, int TN, bool A_F32, bool OUT_BF16>
__global__ __launch_bounds__(256) void gemm32(
    const void* __restrict__ Av, const unsigned short* __restrict__ Bp,
    const float* __restrict__ cvec, void* __restrict__ outv,
    int nValid, long outStride)
{
    constexpr int FM = TM / 64, FN = TN / 64;
    constexpr int SA = TM * 8 / 256, SB = TN * 8 / 256;
    __shared__ unsigned short sA[TM * 64];
    __shared__ unsigned short sB[TN * 64];

    const int t    = threadIdx.x;
    const int lane = t & 63;
    const int w    = t >> 6;
    const int wm   = w >> 1;
    const int wn   = w & 1;
    const int half = lane >> 5;
    const int col  = lane & 31;
    const long m0  = (long)blockIdx.x * TM;
    const long n0  = (long)blockIdx.y * TN;

    f32x16 acc[FM][FN];
#pragma unroll
    for (int i = 0; i < FM; ++i)
#pragma unroll
        for (int j = 0; j < FN; ++j)
            acc[i][j] = (f32x16)(0.f);

    const float*          Af = (const float*)Av;
    const unsigned short* Ab = (const unsigned short*)Av;

    for (int k0 = 0; k0 < KDIM; k0 += 64) {
        // ---- stage A [TM][64] ----
#pragma unroll
        for (int j = 0; j < SA; ++j) {
            int s   = (j * 4 + w) * 64 + lane;
            int row = s >> 3;
            int c   = (s & 7) ^ (row & 7);
            if (A_F32) {
                const float* g = Af + (m0 + row) * KDIM + k0 + c * 8;
                f32x4 v0 = ((const f32x4*)g)[0], v1 = ((const f32x4*)g)[1];
                ushort4 o0, o1;
                o0.x = f2bf(v0.x); o0.y = f2bf(v0.y); o0.z = f2bf(v0.z); o0.w = f2bf(v0.w);
                o1.x = f2bf(v1.x); o1.y = f2bf(v1.y); o1.z = f2bf(v1.z); o1.w = f2bf(v1.w);
                unsigned short* d = &sA[s * 8];
                ((ushort4*)d)[0] = o0; ((ushort4*)d)[1] = o1;
            } else {
                load_lds16(Ab + (m0 + row) * KDIM + k0 + c * 8,
                           &sA[(j * 4 + w) * 64 * 8]);
            }
        }
        // ---- stage B [TN][64] ----
#pragma unroll
        for (int j = 0; j < SB; ++j) {
            int s   = (j * 4 + w) * 64 + lane;
            int row = s >> 3;
            int c   = (s & 7) ^ (row & 7);
            load_lds16(Bp + (n0 + row) * KDIM + k0 + c * 8,
                       &sB[(j * 4 + w) * 64 * 8]);
        }
        __syncthreads();

#pragma unroll
        for (int g = 0; g < 4; ++g) {
            const int c = g * 2 + half;
            bf16x8 af[FM], bfr[FN];
#pragma unroll
            for (int fm = 0; fm < FM; ++fm) {
                int row = wm * (TM / 2) + fm * 32 + col;
                af[fm]  = *(const bf16x8*)&sA[(row * 8 + (c ^ (row & 7))) * 8];
            }
#pragma unroll
            for (int fn = 0; fn < FN; ++fn) {
                int row = wn * (TN / 2) + fn * 32 + col;
                bfr[fn] = *(const bf16x8*)&sB[(row * 8 + (c ^ (row & 7))) * 8];
            }
#pragma unroll
            for (int fm = 0; fm < FM; ++fm)
#pragma unroll
                for (int fn = 0; fn < FN; ++fn)
                    acc[fm][fn] = __builtin_amdgcn_mfma_f32_32x32x16_bf16(
                        af[fm], bfr[fn], acc[fm][fn], 0, 0, 0);
        }
        __syncthreads();
    }

    // ---- epilogue ----
#pragma unroll
    for (int fm = 0; fm < FM; ++fm)
#pragma unroll
        for (int fn = 0; fn < FN; ++fn) {
            long n = n0 + wn * (TN / 2) + fn * 32 + col;
#pragma unroll
            for (int rg = 0; rg < 16; ++rg) {
                long m  = m0 + wm * (TM / 2) + fm * 32
                        + (rg & 3) + 8 * (rg >> 2) + 4 * half;
                float v = acc[fm][fn][rg];
                if (OUT_BF16) {
                    ((unsigned short*)outv)[m * outStride + n] = f2bf(v);
                } else {
                    if (n < nValid)
                        ((float*)outv)[m * outStride + n] = v + cvec[m];
                }
            }
        }
}

extern "C" void kernel_launch(void* const* d_in, const int* in_sizes, int n_in,
                              void* d_out, int out_size, void* d_ws, size_t ws_size,
                              hipStream_t stream) {
    const float* answer = (const float*)d_in[0];   // [640][768] f32
    const float* vocab  = (const float*)d_in[1];   // [30000][768] f32
    const float* W      = (const float*)d_in[2];   // [768][768] f32
    const float* bvec   = (const float*)d_in[3];   // [768] f32

    // ws layout: vocab_bf first so pad-row reads (30000..30079) alias the
    // trailing buffers (read-only pollution of never-stored columns).
    char* ws = (char*)d_ws;
    unsigned short* vocab_bf = (unsigned short*)ws;                                  // 46,080,000 B
    unsigned short* Wt_bf    = (unsigned short*)(ws + 46080000);                     //  1,179,648 B
    unsigned short* A2_bf    = (unsigned short*)(ws + 46080000 + 1179648);           //    983,040 B
    float*          cptr     = (float*)(ws + 46080000 + 1179648 + 983040);           //      2,560 B

    // 1. prep: vocab->bf16, W->Wt bf16, c = A@b
    prep<<<PREP_TOT, 256, 0, stream>>>(vocab, W, answer, bvec,
                                       vocab_bf, Wt_bf, cptr);

    // 2. A2[m][k] = sum_d answer[m][d] * Wt[k][d]   (64x128 tiles, 60 blocks)
    gemm32<64, 128, true, true><<<dim3(MANS / 64, KDIM / 128), 256, 0, stream>>>(
        (const void*)answer, Wt_bf, nullptr, (void*)A2_bf, KDIM, KDIM);

    // 3. out[m][v] = sum_k A2[m][k] * vocab_bf[v][k] + c[m]
    gemm32<128, 128, false, false><<<dim3(MANS / 128, VPAD / 128), 256, 0, stream>>>(
        (const void*)A2_bf, vocab_bf, cptr, d_out, VV, VV);
}

// Round 4
// 231.314 us; speedup vs baseline: 1.2636x; 1.0030x over previous
//
#include <hip/hip_runtime.h>

#define KDIM 768
#define MANS 640      // L*B*T
#define VV   30000
#define NGRP 235      // ceil(30000/128)

typedef __attribute__((ext_vector_type(4)))  float  f32x4;
typedef __attribute__((ext_vector_type(16))) float  f32x16;
typedef __attribute__((ext_vector_type(8)))  __bf16 bf16x8;

__device__ __forceinline__ unsigned short f2bf(float f) {
    union { float f; unsigned int u; } v; v.f = f;
    unsigned int r = v.u + 0x7fffu + ((v.u >> 16) & 1u);  // RNE
    return (unsigned short)(r >> 16);
}

__device__ __forceinline__ void load_lds16(const unsigned short* g, unsigned short* l) {
    __builtin_amdgcn_global_load_lds(
        (__attribute__((address_space(1))) void*)(void*)g,
        (__attribute__((address_space(3))) void*)l,
        16, 0, 0);
}

// ===================== prep_small =====================
// blocks [0,144):   W[768][768] f32 -> Wt[k][d]=W[d][k] bf16 (64x64 tiles)
// blocks [144,304): c[m] = dot(answer[m], b)
__global__ __launch_bounds__(256) void prep_small(
    const float* __restrict__ W, const float* __restrict__ A,
    const float* __restrict__ b, unsigned short* __restrict__ Wt_bf,
    float* __restrict__ cvec)
{
    __shared__ float ts[64][65];
    const int blk = blockIdx.x;
    if (blk < 144) {
        int bx = (blk % 12) * 64, by = (blk / 12) * 64;
        int tx = threadIdx.x & 63, tg = threadIdx.x >> 6;
#pragma unroll
        for (int i = 0; i < 16; ++i) {
            int r = tg * 16 + i;
            ts[r][tx] = W[(long)(by + r) * KDIM + bx + tx];
        }
        __syncthreads();
#pragma unroll
        for (int i = 0; i < 16; ++i) {
            int r = tg * 16 + i;
            Wt_bf[(long)(bx + r) * KDIM + by + tx] = f2bf(ts[tx][r]);
        }
    } else {
        int row  = (blk - 144) * 4 + (threadIdx.x >> 6);
        int lane = threadIdx.x & 63;
        const float* ap = A + (long)row * KDIM;
        float s = 0.f;
#pragma unroll
        for (int i = 0; i < KDIM / 64; ++i) s += ap[i * 64 + lane] * b[i * 64 + lane];
#pragma unroll
        for (int off = 32; off; off >>= 1) s += __shfl_down(s, off, 64);
        if (lane == 0) cvec[row] = s;
    }
}

// ===================== a2 gemm (round-3 structure, 64x128 tile) =====================
// A2[m][k] = sum_d answer[m][d] * Wt[k][d], bf16 out. A f32 cvt in-register.
__global__ __launch_bounds__(256) void gemm_a2(
    const float* __restrict__ Af, const unsigned short* __restrict__ Bp,
    unsigned short* __restrict__ outp)
{
    constexpr int TM = 64, TN = 128;
    __shared__ unsigned short sA[TM * 64];
    __shared__ unsigned short sB[TN * 64];

    const int t    = threadIdx.x;
    const int lane = t & 63;
    const int w    = t >> 6;
    const int wm   = w >> 1;
    const int wn   = w & 1;
    const int half = lane >> 5;
    const int col  = lane & 31;
    const long m0  = (long)blockIdx.x * TM;
    const long n0  = (long)blockIdx.y * TN;

    f32x16 acc[1][2];
    acc[0][0] = (f32x16)(0.f);
    acc[0][1] = (f32x16)(0.f);

    for (int k0 = 0; k0 < KDIM; k0 += 64) {
#pragma unroll
        for (int j = 0; j < 2; ++j) {        // A: 512 chunks, f32 -> bf16
            int s   = (j * 4 + w) * 64 + lane;
            int row = s >> 3;
            int c   = (s & 7) ^ (row & 7);
            const float* g = Af + (m0 + row) * KDIM + k0 + c * 8;
            f32x4 v0 = ((const f32x4*)g)[0], v1 = ((const f32x4*)g)[1];
            ushort4 o0, o1;
            o0.x = f2bf(v0.x); o0.y = f2bf(v0.y); o0.z = f2bf(v0.z); o0.w = f2bf(v0.w);
            o1.x = f2bf(v1.x); o1.y = f2bf(v1.y); o1.z = f2bf(v1.z); o1.w = f2bf(v1.w);
            unsigned short* d = &sA[s * 8];
            ((ushort4*)d)[0] = o0; ((ushort4*)d)[1] = o1;
        }
#pragma unroll
        for (int j = 0; j < 4; ++j) {        // B: 1024 chunks via DMA
            int s   = (j * 4 + w) * 64 + lane;
            int row = s >> 3;
            int c   = (s & 7) ^ (row & 7);
            load_lds16(Bp + (n0 + row) * KDIM + k0 + c * 8,
                       &sB[(j * 4 + w) * 64 * 8]);
        }
        __syncthreads();

#pragma unroll
        for (int g = 0; g < 4; ++g) {
            const int cg = g * 2 + half;
            int arow = wm * 32 + col;        // TM/2 = 32
            bf16x8 af = *(const bf16x8*)&sA[(arow * 8 + (cg ^ (arow & 7))) * 8];
#pragma unroll
            for (int fn = 0; fn < 2; ++fn) {
                int brow = wn * 64 + fn * 32 + col;
                bf16x8 bf = *(const bf16x8*)&sB[(brow * 8 + (cg ^ (brow & 7))) * 8];
                acc[0][fn] = __builtin_amdgcn_mfma_f32_32x32x16_bf16(
                    af, bf, acc[0][fn], 0, 0, 0);
            }
        }
        __syncthreads();
    }

#pragma unroll
    for (int fn = 0; fn < 2; ++fn) {
        long n = n0 + wn * 64 + fn * 32 + col;
#pragma unroll
        for (int rg = 0; rg < 16; ++rg) {
            long m = m0 + wm * 32 + (rg & 3) + 8 * (rg >> 2) + 4 * half;
            outp[m * KDIM + n] = f2bf(acc[0][fn][rg]);
        }
    }
}

// ===================== big gemm: out = A2 @ vocab^T + c =====================
// 128x128 tile, BK=64. B = vocab f32, converted in-staging. A = A2 bf16 via DMA.
// XCD-grouping: id%8 = XCD (heuristic); the 5 m-blocks of one n-group share an
// XCD and a ~32-id dispatch window -> vocab f32 tile fetched once per device.
__global__ __launch_bounds__(256) void gemm_big(
    const unsigned short* __restrict__ A, const float* __restrict__ Bf,
    const float* __restrict__ cvec, float* __restrict__ outp)
{
    const int id    = blockIdx.x;
    const int x     = id & 7;
    const int q     = id >> 3;
    const int m_idx = q % 5;
    const int n_grp = (q / 5) * 8 + x;
    if (n_grp >= NGRP) return;               // 25 pad blocks idle

    __shared__ unsigned short sA[128 * 64];  // 16 KB
    __shared__ unsigned short sB[128 * 64];  // 16 KB

    const int t    = threadIdx.x;
    const int lane = t & 63;
    const int w    = t >> 6;
    const int wm   = w >> 1;
    const int wn   = w & 1;
    const int half = lane >> 5;
    const int col  = lane & 31;
    const long m0  = (long)m_idx * 128;
    const long n0  = (long)n_grp * 128;

    f32x16 acc[2][2];
#pragma unroll
    for (int i = 0; i < 2; ++i)
#pragma unroll
        for (int j = 0; j < 2; ++j) acc[i][j] = (f32x16)(0.f);

    // A staging: 1024 chunks via DMA, source XOR-swizzled
    const unsigned short* ga[4];
    unsigned short*       la[4];
#pragma unroll
    for (int j = 0; j < 4; ++j) {
        int s  = (j * 4 + w) * 64 + lane;
        int row = s >> 3;
        int c   = (s & 7) ^ (row & 7);
        ga[j] = A + (m0 + row) * KDIM + c * 8;
        la[j] = &sA[(j * 4 + w) * 64 * 8];
    }
    // B staging: 1024 chunks, manual f32->bf16 (row clamped to 29999)
    const float* gb[4];
    unsigned short* lb[4];
#pragma unroll
    for (int j = 0; j < 4; ++j) {
        int s   = j * 256 + t;
        int row = s >> 3;
        int c   = (s & 7) ^ (row & 7);
        long grow = n0 + row;
        if (grow > VV - 1) grow = VV - 1;
        gb[j] = Bf + grow * KDIM + c * 8;
        lb[j] = &sB[s * 8];
    }

    for (int k0 = 0; k0 < KDIM; k0 += 64) {
#pragma unroll
        for (int j = 0; j < 4; ++j) load_lds16(ga[j] + k0, la[j]);
#pragma unroll
        for (int j = 0; j < 4; ++j) {
            const float* g = gb[j] + k0;
            f32x4 v0 = ((const f32x4*)g)[0], v1 = ((const f32x4*)g)[1];
            ushort4 o0, o1;
            o0.x = f2bf(v0.x); o0.y = f2bf(v0.y); o0.z = f2bf(v0.z); o0.w = f2bf(v0.w);
            o1.x = f2bf(v1.x); o1.y = f2bf(v1.y); o1.z = f2bf(v1.z); o1.w = f2bf(v1.w);
            ((ushort4*)lb[j])[0] = o0; ((ushort4*)lb[j])[1] = o1;
        }
        __syncthreads();

#pragma unroll
        for (int g = 0; g < 4; ++g) {
            const int cg = g * 2 + half;
            bf16x8 af[2], bfr[2];
#pragma unroll
            for (int fm = 0; fm < 2; ++fm) {
                int row = wm * 64 + fm * 32 + col;
                af[fm]  = *(const bf16x8*)&sA[(row * 8 + (cg ^ (row & 7))) * 8];
            }
#pragma unroll
            for (int fn = 0; fn < 2; ++fn) {
                int row = wn * 64 + fn * 32 + col;
                bfr[fn] = *(const bf16x8*)&sB[(row * 8 + (cg ^ (row & 7))) * 8];
            }
#pragma unroll
            for (int fm = 0; fm < 2; ++fm)
#pragma unroll
                for (int fn = 0; fn < 2; ++fn)
                    acc[fm][fn] = __builtin_amdgcn_mfma_f32_32x32x16_bf16(
                        af[fm], bfr[fn], acc[fm][fn], 0, 0, 0);
        }
        __syncthreads();
    }

#pragma unroll
    for (int fm = 0; fm < 2; ++fm)
#pragma unroll
        for (int fn = 0; fn < 2; ++fn) {
            long n = n0 + wn * 64 + fn * 32 + col;
            if (n < VV) {
#pragma unroll
                for (int rg = 0; rg < 16; ++rg) {
                    long m = m0 + wm * 64 + fm * 32
                           + (rg & 3) + 8 * (rg >> 2) + 4 * half;
                    outp[m * (long)VV + n] = acc[fm][fn][rg] + cvec[m];
                }
            }
        }
}

extern "C" void kernel_launch(void* const* d_in, const int* in_sizes, int n_in,
                              void* d_out, int out_size, void* d_ws, size_t ws_size,
                              hipStream_t stream) {
    const float* answer = (const float*)d_in[0];   // [640][768] f32
    const float* vocab  = (const float*)d_in[1];   // [30000][768] f32
    const float* W      = (const float*)d_in[2];   // [768][768] f32
    const float* bvec   = (const float*)d_in[3];   // [768] f32

    char* ws = (char*)d_ws;
    unsigned short* Wt_bf = (unsigned short*)ws;                    // 1,179,648 B
    unsigned short* A2_bf = (unsigned short*)(ws + 1179648);        //   983,040 B
    float*          cptr  = (float*)(ws + 1179648 + 983040);        //     2,560 B

    // 1. Wt = W^T (bf16), c = answer @ b
    prep_small<<<304, 256, 0, stream>>>(W, answer, bvec, Wt_bf, cptr);

    // 2. A2[m][k] = sum_d answer[m][d] * Wt[k][d]   (60 blocks)
    gemm_a2<<<dim3(MANS / 64, KDIM / 128), 256, 0, stream>>>(answer, Wt_bf, A2_bf);

    // 3. out[m][v] = sum_k A2[m][k] * vocab_bf16(v,k) + c[m]
    //    1200 blocks (25 idle), XCD-grouped swizzle inside.
    gemm_big<<<1200, 256, 0, stream>>>(A2_bf, vocab, cptr, (float*)d_out);
}